// Round 15
// baseline (591.862 us; speedup 1.0000x reference)
//
#include <hip/hip_runtime.h>
#include <hip/hip_bf16.h>
#include <cstdint>
#include <cstddef>

// LinearCrypto MI355X round 15: r14 + LDS diet for GEMMs — Cs epilogue done in
// two 64-row halves so LDS = exactly 32768B -> 5 blocks/CU (was 4).
// B=64, F=512, L=512, P=96, H=8, hd=64, M=B*512=32768

#define EPS_ATTN 1e-6f
#define EPS_LN   1e-5f
#define EPS_REVIN 1e-5f

typedef __attribute__((ext_vector_type(8))) short bf16x8;
typedef __attribute__((ext_vector_type(4))) float f32x4;
typedef __attribute__((ext_vector_type(8))) unsigned short u16x8;

__device__ __forceinline__ float bf2f(unsigned short u) {
  unsigned int x = ((unsigned int)u) << 16;
  return __builtin_bit_cast(float, x);
}
__device__ __forceinline__ unsigned short f2bf(float f) {
  __hip_bfloat16 h = __float2bfloat16(f);
  return __builtin_bit_cast(unsigned short, h);
}
__device__ __forceinline__ void gload16(const void* g, void* l) {
  __builtin_amdgcn_global_load_lds(
      (const __attribute__((address_space(1))) void*)g,
      (__attribute__((address_space(3))) void*)l, 16, 0, 0);
}

// ---------- RevIN stats + normalized bf16 copy xn (B,F,L) ----------
__global__ __launch_bounds__(256) void revin_xn_k(const float* __restrict__ x,
                                                  const float* __restrict__ rg,
                                                  const float* __restrict__ rb,
                                                  float* __restrict__ meanb,
                                                  float* __restrict__ stdb,
                                                  unsigned short* __restrict__ xn) {
  int wid = threadIdx.x >> 6, lane = threadIdx.x & 63;
  int row = blockIdx.x * 4 + wid;               // b*512 + f
  const float* xr = x + (size_t)row * 512 + lane * 8;
  float4 a = *(const float4*)xr;
  float4 c = *(const float4*)(xr + 4);
  float s1 = a.x + a.y + a.z + a.w + c.x + c.y + c.z + c.w;
  float s2 = a.x * a.x + a.y * a.y + a.z * a.z + a.w * a.w +
             c.x * c.x + c.y * c.y + c.z * c.z + c.w * c.w;
#pragma unroll
  for (int off = 1; off < 64; off <<= 1) { s1 += __shfl_xor(s1, off); s2 += __shfl_xor(s2, off); }
  float m = s1 * (1.f / 512.f);
  float var = fmaxf((s2 - 512.f * m * m) * (1.f / 511.f), 0.f);
  float sd = sqrtf(var) + EPS_REVIN;
  int f = row & 511;
  float sc = rg[f] / sd;
  float of = rb[f] - m * sc;
  u16x8 o;
  o[0] = f2bf(a.x * sc + of); o[1] = f2bf(a.y * sc + of);
  o[2] = f2bf(a.z * sc + of); o[3] = f2bf(a.w * sc + of);
  o[4] = f2bf(c.x * sc + of); o[5] = f2bf(c.y * sc + of);
  o[6] = f2bf(c.z * sc + of); o[7] = f2bf(c.w * sc + of);
  *(u16x8*)(xn + (size_t)row * 512 + lane * 8) = o;
  if (lane == 0) { meanb[row] = m; stdb[row] = sd; }
}

// ---------- fused transpose + LayerNorm: xn (B,F,L) -> abf (B,L,F) LN'd ----------
__global__ __launch_bounds__(256) void tln_k(const unsigned short* __restrict__ xn,
                                             const float* __restrict__ g,
                                             const float* __restrict__ bq,
                                             unsigned short* __restrict__ o16) {
  __shared__ unsigned short Ts[32][528] __attribute__((aligned(16)));
  const int b = blockIdx.y, l0 = blockIdx.x * 32;
  const int tid = threadIdx.x;
#pragma unroll
  for (int it = 0; it < 8; ++it) {
    int idx = it * 256 + tid;
    int f = idx >> 2, lc = (idx & 3) * 8;
    u16x8 v = *(const u16x8*)(xn + ((size_t)b * 512 + f) * 512 + l0 + lc);
#pragma unroll
    for (int j = 0; j < 8; ++j) Ts[lc + j][f] = v[j];
  }
  __syncthreads();
  const int l = tid >> 3, q = tid & 7;
  float s1 = 0.f, s2 = 0.f;
#pragma unroll
  for (int i = 0; i < 8; ++i) {
    int c = (i + q) & 7;
    bf16x8 t = *(const bf16x8*)&Ts[l][q * 64 + c * 8];
#pragma unroll
    for (int j = 0; j < 8; ++j) {
      float x = bf2f((unsigned short)t[j]);
      s1 += x; s2 += x * x;
    }
  }
#pragma unroll
  for (int off = 1; off < 8; off <<= 1) { s1 += __shfl_xor(s1, off); s2 += __shfl_xor(s2, off); }
  float m = s1 * (1.f / 512.f);
  float var = fmaxf(s2 * (1.f / 512.f) - m * m, 0.f);
  float iv = 1.f / sqrtf(var + EPS_LN);
#pragma unroll
  for (int i = 0; i < 8; ++i) {
    int c = (i + q) & 7;
    int f8 = q * 64 + c * 8;
    bf16x8 t = *(const bf16x8*)&Ts[l][f8];
    float4 g0 = *(const float4*)(g + f8);
    float4 g1 = *(const float4*)(g + f8 + 4);
    float4 b0 = *(const float4*)(bq + f8);
    float4 b1 = *(const float4*)(bq + f8 + 4);
    u16x8 o;
    o[0] = f2bf((bf2f((unsigned short)t[0]) - m) * iv * g0.x + b0.x);
    o[1] = f2bf((bf2f((unsigned short)t[1]) - m) * iv * g0.y + b0.y);
    o[2] = f2bf((bf2f((unsigned short)t[2]) - m) * iv * g0.z + b0.z);
    o[3] = f2bf((bf2f((unsigned short)t[3]) - m) * iv * g0.w + b0.w);
    o[4] = f2bf((bf2f((unsigned short)t[4]) - m) * iv * g1.x + b1.x);
    o[5] = f2bf((bf2f((unsigned short)t[5]) - m) * iv * g1.y + b1.y);
    o[6] = f2bf((bf2f((unsigned short)t[6]) - m) * iv * g1.z + b1.z);
    o[7] = f2bf((bf2f((unsigned short)t[7]) - m) * iv * g1.w + b1.w);
    *(u16x8*)&Ts[l][f8] = o;
  }
  __syncthreads();
#pragma unroll
  for (int it = 0; it < 8; ++it) {
    int idx = it * 256 + tid;
    int ll = idx >> 6, f8 = (idx & 63) * 8;
    u16x8 v = *(const u16x8*)&Ts[ll][f8];
    *(u16x8*)(o16 + ((size_t)b * 512 + l0 + ll) * 512 + f8) = v;
  }
}

// ---------- fused LayerNorm bf16 -> bf16 ----------
__global__ __launch_bounds__(256) void ln_k(const unsigned short* __restrict__ in,
                                            const float* __restrict__ g,
                                            const float* __restrict__ bq,
                                            unsigned short* __restrict__ o16) {
  int row = blockIdx.x * 4 + (threadIdx.x >> 6);
  int lane = threadIdx.x & 63;
  u16x8 u = *(const u16x8*)(in + (size_t)row * 512 + lane * 8);
  float v[8];
#pragma unroll
  for (int j = 0; j < 8; ++j) v[j] = bf2f(u[j]);
  float s1 = 0.f, s2 = 0.f;
#pragma unroll
  for (int j = 0; j < 8; ++j) { s1 += v[j]; s2 += v[j] * v[j]; }
#pragma unroll
  for (int off = 1; off < 64; off <<= 1) { s1 += __shfl_xor(s1, off); s2 += __shfl_xor(s2, off); }
  float m = s1 * (1.f / 512.f);
  float var = fmaxf(s2 * (1.f / 512.f) - m * m, 0.f);
  float iv = 1.f / sqrtf(var + EPS_LN);
  float4 g0 = *(const float4*)(g + lane * 8);
  float4 g1 = *(const float4*)(g + lane * 8 + 4);
  float4 b0 = *(const float4*)(bq + lane * 8);
  float4 b1 = *(const float4*)(bq + lane * 8 + 4);
  u16x8 o;
  o[0] = f2bf((v[0] - m) * iv * g0.x + b0.x);
  o[1] = f2bf((v[1] - m) * iv * g0.y + b0.y);
  o[2] = f2bf((v[2] - m) * iv * g0.z + b0.z);
  o[3] = f2bf((v[3] - m) * iv * g0.w + b0.w);
  o[4] = f2bf((v[4] - m) * iv * g1.x + b1.x);
  o[5] = f2bf((v[5] - m) * iv * g1.y + b1.y);
  o[6] = f2bf((v[6] - m) * iv * g1.z + b1.z);
  o[7] = f2bf((v[7] - m) * iv * g1.w + b1.w);
  *(u16x8*)(o16 + (size_t)row * 512 + lane * 8) = o;
}

// ---------- convert 8 (512x512) fp32 weights -> bf16 packed ----------
__global__ __launch_bounds__(256) void wconv_k(const float* w0, const float* w1,
                                               const float* w2, const float* w3,
                                               const float* w4, const float* w5,
                                               const float* w6, const float* w7,
                                               unsigned short* __restrict__ out) {
  const float* srcs[8] = {w0, w1, w2, w3, w4, w5, w6, w7};
  const float* s = srcs[blockIdx.y];
  size_t idx = (size_t)blockIdx.x * 2048 + threadIdx.x * 8;
  float4 v0 = *(const float4*)(s + idx);
  float4 v1 = *(const float4*)(s + idx + 4);
  u16x8 o;
  o[0] = f2bf(v0.x); o[1] = f2bf(v0.y); o[2] = f2bf(v0.z); o[3] = f2bf(v0.w);
  o[4] = f2bf(v1.x); o[5] = f2bf(v1.y); o[6] = f2bf(v1.z); o[7] = f2bf(v1.w);
  *(u16x8*)(out + (size_t)blockIdx.y * 262144 + idx) = o;
}

// ---------- GEMM core (r9: single-buffer BK=64, 2 barriers/K-step) ----------
// smem layout: A tile [0,8192) shorts, B tile [8192,16384) shorts = 32768 B.
__device__ __forceinline__ void gemm_core(const unsigned short* __restrict__ A,
                                          const unsigned short* __restrict__ W,
                                          unsigned short* smem,
                                          f32x4 (&acc)[4][4],
                                          int m0, int wrow, int tid) {
  const int w = tid >> 6, lane = tid & 63;
  const int wr = w >> 1, wc = w & 1;
  const int r8 = lane >> 3, s8 = lane & 7, gslot = s8 ^ r8;
  const unsigned short* Ag = A + (size_t)(m0 + w * 32 + r8) * 512 + gslot * 8;
  const unsigned short* Wg = W + (size_t)(wrow + w * 32 + r8) * 512 + gslot * 8;
  unsigned short* Asw = smem + w * 2048;
  unsigned short* Bsw = smem + 8192 + w * 2048;
  for (int k0 = 0; k0 < 512; k0 += 64) {
#pragma unroll
    for (int c = 0; c < 4; ++c) {
      gload16(Ag + (size_t)c * 8 * 512 + k0, Asw + c * 512);
      gload16(Wg + (size_t)c * 8 * 512 + k0, Bsw + c * 512);
    }
    __syncthreads();
#pragma unroll
    for (int s = 0; s < 2; ++s) {
      bf16x8 fa[4], fb[4];
#pragma unroll
      for (int i = 0; i < 4; ++i) {
        int ra = wr * 64 + i * 16 + (lane & 15);
        int sa = (s * 4 + (lane >> 4)) ^ (ra & 7);
        fa[i] = *(const bf16x8*)&smem[ra * 64 + sa * 8];
        int rb = wc * 64 + i * 16 + (lane & 15);
        int sb = (s * 4 + (lane >> 4)) ^ (rb & 7);
        fb[i] = *(const bf16x8*)&smem[8192 + rb * 64 + sb * 8];
      }
#pragma unroll
      for (int i = 0; i < 4; ++i)
#pragma unroll
        for (int j = 0; j < 4; ++j)
          acc[i][j] = __builtin_amdgcn_mfma_f32_16x16x32_bf16(fa[i], fb[j], acc[i][j], 0, 0, 0);
    }
    __syncthreads();
  }
}

// ---------- half-tile epilogue: Cs is 64x136 (17408 B), two passes ----------
template <int TRANS, int ACT, int RES>
__device__ __forceinline__ void gemm_epilogue(f32x4 (&acc)[4][4],
                                              unsigned short* Cs,   // [64][136]
                                              const float* __restrict__ bias,
                                              const unsigned short* __restrict__ resid,
                                              unsigned short* __restrict__ out,
                                              int m0, int n0, int tid) {
  const int w = tid >> 6, lane = tid & 63;
  const int wr = w >> 1, wc = w & 1;
  const int ro = (lane >> 4) * 4, c16 = lane & 15;
  const int splitw = TRANS ? wc : wr;
  size_t rowbase; int colbase;
  if constexpr (TRANS) { rowbase = (size_t)((m0 >> 9) * 512 + n0); colbase = m0 & 511; }
  else                 { rowbase = (size_t)m0; colbase = n0; }
#pragma unroll
  for (int half = 0; half < 2; ++half) {
    __syncthreads();
    if (splitw == half) {
#pragma unroll
      for (int j = 0; j < 4; ++j) {
        int nl = wc * 64 + j * 16 + c16;
        float bi = bias[n0 + nl];
#pragma unroll
        for (int i = 0; i < 4; ++i) {
#pragma unroll
          for (int r = 0; r < 4; ++r) {
            float v = acc[i][j][r] + bi;
            if constexpr (ACT) v = (v > 0.f) ? v + 1.f : __expf(v);
            if constexpr (TRANS) Cs[(j * 16 + c16) * 136 + wr * 64 + i * 16 + ro + r] = f2bf(v);
            else                 Cs[(i * 16 + ro + r) * 136 + nl] = f2bf(v);
          }
        }
      }
    }
    __syncthreads();
#pragma unroll
    for (int c = 0; c < 4; ++c) {
      int idx = c * 256 + tid;
      int rr = idx >> 4, c8 = (idx & 15) * 8;
      u16x8 v = *(const u16x8*)&Cs[rr * 136 + c8];
      size_t gaddr = (rowbase + half * 64 + rr) * 512 + colbase + c8;
      if constexpr (RES) {
        u16x8 rv = *(const u16x8*)(resid + gaddr);
#pragma unroll
        for (int q = 0; q < 8; ++q) v[q] = f2bf(bf2f(v[q]) + bf2f(rv[q]));
      }
      *(u16x8*)(out + gaddr) = v;
    }
  }
}

// ---------- standard GEMM dispatch (Wo): 1D grid 1024, XCD-chunked, n-inner ----------
template <int TRANS, int ACT, int RES>
__global__ __launch_bounds__(256, 5) void gemm_std_k(const unsigned short* __restrict__ A,
                                                     const unsigned short* __restrict__ W,
                                                     const float* __restrict__ bias,
                                                     const unsigned short* __restrict__ resid,
                                                     unsigned short* __restrict__ out) {
  __shared__ unsigned short smem[16384] __attribute__((aligned(16)));   // 32768 B
  const int tid = threadIdx.x;
  const int bid = blockIdx.x;
  const int nb = (bid & 7) * 128 + (bid >> 3);   // bijective, 1024 % 8 == 0
  const int m0 = (nb >> 2) * 128;
  const int n0 = (nb & 3) * 128;
  f32x4 acc[4][4] = {};
  gemm_core(A, W, smem, acc, m0, n0, tid);
  gemm_epilogue<TRANS, ACT, RES>(acc, smem, bias, resid, out, m0, n0, tid);
}

// ---------- fused QKV GEMM: grid 3072, 12 n-tiles per A-panel adjacent ----------
__global__ __launch_bounds__(256, 5) void gemm_qkv3_k(const unsigned short* __restrict__ A,
                                                      const unsigned short* __restrict__ Wqkv,
                                                      const float* __restrict__ bq,
                                                      const float* __restrict__ bk,
                                                      const float* __restrict__ bv,
                                                      unsigned short* __restrict__ Q,
                                                      unsigned short* __restrict__ K,
                                                      unsigned short* __restrict__ V) {
  __shared__ unsigned short smem[16384] __attribute__((aligned(16)));   // 32768 B
  const int tid = threadIdx.x;
  const unsigned int bid = blockIdx.x;
  const unsigned int nb = (bid & 7) * 384 + (bid >> 3);  // bijective, 3072 % 8 == 0
  const int mi = nb / 12, ni = nb % 12;                  // 12 consecutive share A-panel
  const int m0 = mi * 128;
  const int mat = ni >> 2;                               // 0=Q, 1=K, 2=V
  const int n0 = (ni & 3) * 128;
  f32x4 acc[4][4] = {};
  gemm_core(A, Wqkv, smem, acc, m0, mat * 512 + n0, tid);

  const float* bias = (mat == 0) ? bq : (mat == 1) ? bk : bv;
  unsigned short* out = (mat == 0) ? Q : (mat == 1) ? K : V;
  const bool trans = (mat > 0);
  const bool act = (mat < 2);

  const int w = tid >> 6, lane = tid & 63;
  const int wr = w >> 1, wc = w & 1;
  const int ro = (lane >> 4) * 4, c16 = lane & 15;
  unsigned short* Cs = smem;
  const int splitw = trans ? wc : wr;
  size_t rowbase = trans ? (size_t)((m0 >> 9) * 512 + n0) : (size_t)m0;
  int colbase = trans ? (m0 & 511) : n0;
#pragma unroll
  for (int half = 0; half < 2; ++half) {
    __syncthreads();
    if (splitw == half) {
#pragma unroll
      for (int j = 0; j < 4; ++j) {
        int nl = wc * 64 + j * 16 + c16;
        float bi = bias[n0 + nl];
#pragma unroll
        for (int i = 0; i < 4; ++i) {
#pragma unroll
          for (int r = 0; r < 4; ++r) {
            float v = acc[i][j][r] + bi;
            if (act) v = (v > 0.f) ? v + 1.f : __expf(v);
            if (trans) Cs[(j * 16 + c16) * 136 + wr * 64 + i * 16 + ro + r] = f2bf(v);
            else       Cs[(i * 16 + ro + r) * 136 + nl] = f2bf(v);
          }
        }
      }
    }
    __syncthreads();
#pragma unroll
    for (int c = 0; c < 4; ++c) {
      int idx = c * 256 + tid;
      int rr = idx >> 4, c8 = (idx & 15) * 8;
      u16x8 v = *(const u16x8*)&Cs[rr * 136 + c8];
      *(u16x8*)(out + (rowbase + half * 64 + rr) * 512 + colbase + c8) = v;
    }
  }
}

// ---------- fused kv+attn: per (b,h): KVT+Z in LDS, then O in-place over Q ----------
__global__ __launch_bounds__(256) void kv_attn_k(unsigned short* __restrict__ Q16,
                                                 const unsigned short* __restrict__ KT,
                                                 const unsigned short* __restrict__ VT) {
  __shared__ unsigned short kvs[4096] __attribute__((aligned(16)));  // 64 e x 128B
  __shared__ float Zs[64];
  const int bh = blockIdx.x, b = bh >> 3, h = bh & 7;
  const int tid = threadIdx.x, w = tid >> 6, lane = tid & 63;
  const int r16 = lane & 15, g = lane >> 4;

  // phase 1: KVT[e][d] = sum_n VT[e][n]*KT[d][n]; Z[d] = sum_n KT[d][n]
  const unsigned short* vb = VT + ((size_t)bh * 64 + w * 16 + r16) * 512 + g * 8;
  const unsigned short* kb = KT + ((size_t)bh * 64 + r16) * 512 + g * 8;
  const short ob = (short)0x3F80;                 // bf16 1.0
  const bf16x8 onesf = {ob, ob, ob, ob, ob, ob, ob, ob};
  f32x4 acc[4] = {}, zacc[4] = {};
  for (int n0 = 0; n0 < 512; n0 += 32) {
    bf16x8 vf = *(const bf16x8*)(vb + n0);
#pragma unroll
    for (int j = 0; j < 4; ++j) {
      bf16x8 kf = *(const bf16x8*)(kb + (size_t)j * 16 * 512 + n0);
      acc[j] = __builtin_amdgcn_mfma_f32_16x16x32_bf16(vf, kf, acc[j], 0, 0, 0);
      zacc[j] = __builtin_amdgcn_mfma_f32_16x16x32_bf16(onesf, kf, zacc[j], 0, 0, 0);
    }
  }
#pragma unroll
  for (int j = 0; j < 4; ++j)
#pragma unroll
    for (int r = 0; r < 4; ++r) {
      int e = w * 16 + g * 4 + r, d = j * 16 + r16;
      int byte = e * 128 + ((((d >> 3) ^ (e & 7)) << 4)) + (d & 7) * 2;
      *(unsigned short*)((char*)kvs + byte) = f2bf(acc[j][r]);
    }
  if (w == 0 && g == 0) {
#pragma unroll
    for (int j = 0; j < 4; ++j) Zs[j * 16 + r16] = zacc[j][0];
  }
  __syncthreads();

  // phase 2: O = (Q @ KVT^T)/(Q.Z+eps); wave w owns rows w*128..+128 of batch b
#pragma unroll
  for (int i = 0; i < 8; ++i) {
    int mrow = b * 512 + w * 128 + i * 16;
    const unsigned short* qrow = Q16 + (size_t)(mrow + r16) * 512 + h * 64;
    bf16x8 q0 = *(const bf16x8*)(qrow + g * 8);
    bf16x8 q1 = *(const bf16x8*)(qrow + 32 + g * 8);
    float np = 0.f;
#pragma unroll
    for (int q = 0; q < 8; ++q) np = fmaf(bf2f((unsigned short)q0[q]), Zs[g * 8 + q], np);
#pragma unroll
    for (int q = 0; q < 8; ++q) np = fmaf(bf2f((unsigned short)q1[q]), Zs[32 + g * 8 + q], np);
    f32x4 a2[4] = {};
#pragma unroll
    for (int j = 0; j < 4; ++j) {
      int e = j * 16 + r16;
      int byte0 = e * 128, sw = (e & 7) << 4;
      bf16x8 k0 = *(const bf16x8*)((char*)kvs + ((byte0 + g * 16) ^ sw));
      bf16x8 k1 = *(const bf16x8*)((char*)kvs + ((byte0 + 64 + g * 16) ^ sw));
      a2[j] = __builtin_amdgcn_mfma_f32_16x16x32_bf16(q0, k0, a2[j], 0, 0, 0);
      a2[j] = __builtin_amdgcn_mfma_f32_16x16x32_bf16(q1, k1, a2[j], 0, 0, 0);
    }
    np += __shfl_xor(np, 16);
    np += __shfl_xor(np, 32);
    float inv = 1.f / (np + EPS_ATTN);
    float inv4[4];
#pragma unroll
    for (int r = 0; r < 4; ++r) inv4[r] = __shfl(inv, g * 4 + r);
    int orow0 = mrow + g * 4;
#pragma unroll
    for (int j = 0; j < 4; ++j)
#pragma unroll
      for (int r = 0; r < 4; ++r)
        Q16[(size_t)(orow0 + r) * 512 + h * 64 + j * 16 + r16] = f2bf(a2[j][r] * inv4[r]);
  }
}

// ---------- feat_linear via MFMA ----------
__global__ __launch_bounds__(256) void feat_linear_k(const unsigned short* __restrict__ h3,
                                                     const float* __restrict__ Wlin,
                                                     const float* __restrict__ blin,
                                                     float* __restrict__ Y) {
  __shared__ unsigned short As[64 * 64] __attribute__((aligned(16)));
  __shared__ unsigned short Bs[96 * 64] __attribute__((aligned(16)));
  const int f = blockIdx.x;
  const int tid = threadIdx.x;
  const int w = tid >> 6, lane = tid & 63;
  const int r16 = lane & 15, g = lane >> 4;
  const int r8 = lane >> 3, s8 = lane & 7, gs = s8 ^ r8;

  f32x4 acc[6] = {};
  for (int k0 = 0; k0 < 512; k0 += 64) {
#pragma unroll
    for (int c = 0; c < 2; ++c) {
      int row = w * 16 + c * 8 + r8;
      gload16(h3 + ((size_t)row * 512 + f) * 512 + k0 + gs * 8,
              As + (w * 16 + c * 8) * 64);
    }
#pragma unroll
    for (int it = 0; it < 3; ++it) {
      int idx = it * 256 + tid;
      int pp = idx >> 3, sl = idx & 7;
      const float* src = Wlin + ((size_t)f * 96 + pp) * 512 + k0 + sl * 8;
      float4 v0 = *(const float4*)src;
      float4 v1 = *(const float4*)(src + 4);
      u16x8 o;
      o[0] = f2bf(v0.x); o[1] = f2bf(v0.y); o[2] = f2bf(v0.z); o[3] = f2bf(v0.w);
      o[4] = f2bf(v1.x); o[5] = f2bf(v1.y); o[6] = f2bf(v1.z); o[7] = f2bf(v1.w);
      *(u16x8*)&Bs[pp * 64 + (sl ^ (pp & 7)) * 8] = o;
    }
    __syncthreads();
#pragma unroll
    for (int s = 0; s < 2; ++s) {
      int arow = w * 16 + r16;
      bf16x8 fa = *(const bf16x8*)&As[arow * 64 + (((s * 4 + g) ^ (arow & 7)) * 8)];
#pragma unroll
      for (int n = 0; n < 6; ++n) {
        int brow = n * 16 + r16;
        bf16x8 fb = *(const bf16x8*)&Bs[brow * 64 + (((s * 4 + g) ^ (brow & 7)) * 8)];
        acc[n] = __builtin_amdgcn_mfma_f32_16x16x32_bf16(fa, fb, acc[n], 0, 0, 0);
      }
    }
    __syncthreads();
  }
  const int b0 = w * 16 + g * 4;
#pragma unroll
  for (int n = 0; n < 6; ++n) {
    float bi = blin[f * 96 + n * 16 + r16];
#pragma unroll
    for (int r = 0; r < 4; ++r)
      Y[((size_t)(b0 + r) * 512 + f) * 96 + n * 16 + r16] = acc[n][r] + bi;
  }
}

// ---------- final: denorm + projector ----------
__global__ __launch_bounds__(256) void final_out_k(const float* __restrict__ Y,
                                                   const float* __restrict__ meanb,
                                                   const float* __restrict__ stdb,
                                                   const float* __restrict__ rg,
                                                   const float* __restrict__ rb,
                                                   const float* __restrict__ Wproj,
                                                   const float* __restrict__ bproj,
                                                   float* __restrict__ out) {
  int b = blockIdx.x;
  __shared__ float cs[512];
  __shared__ float kred[4];
  int t = threadIdx.x;
  float kpart = 0.f;
  for (int f = t; f < 512; f += 256) {
    float sd = stdb[b * 512 + f], mn = meanb[b * 512 + f];
    float g = rg[f], rbv = rb[f], wp = Wproj[f];
    float c = wp * sd / g;
    cs[f] = c;
    kpart += wp * mn - c * rbv;
  }
#pragma unroll
  for (int off = 32; off; off >>= 1) kpart += __shfl_down(kpart, off);
  int wid = t >> 6, lane = t & 63;
  if (lane == 0) kred[wid] = kpart;
  __syncthreads();
  float K = kred[0] + kred[1] + kred[2] + kred[3] + bproj[0];
  if (t < 96) {
    float acc = 0.f;
    for (int f = 0; f < 512; ++f) acc = fmaf(cs[f], Y[((size_t)b * 512 + f) * 96 + t], acc);
    out[b * 96 + t] = acc + K;
  }
}

extern "C" void kernel_launch(void* const* d_in, const int* in_sizes, int n_in,
                              void* d_out, int out_size, void* d_ws, size_t ws_size,
                              hipStream_t stream) {
  const float* x    = (const float*)d_in[0];
  const float* rg   = (const float*)d_in[1];
  const float* rb   = (const float*)d_in[2];
  const float* n1g  = (const float*)d_in[3];
  const float* n1b  = (const float*)d_in[4];
  const float* n2g  = (const float*)d_in[5];
  const float* n2b  = (const float*)d_in[6];
  const float* tWq  = (const float*)d_in[7];
  const float* tbq  = (const float*)d_in[8];
  const float* tWk  = (const float*)d_in[9];
  const float* tbk  = (const float*)d_in[10];
  const float* tWv  = (const float*)d_in[11];
  const float* tbv  = (const float*)d_in[12];
  const float* tWo  = (const float*)d_in[13];
  const float* tbo  = (const float*)d_in[14];
  const float* fWq  = (const float*)d_in[15];
  const float* fbq  = (const float*)d_in[16];
  const float* fWk  = (const float*)d_in[17];
  const float* fbk  = (const float*)d_in[18];
  const float* fWv  = (const float*)d_in[19];
  const float* fbv  = (const float*)d_in[20];
  const float* fWo  = (const float*)d_in[21];
  const float* fbo  = (const float*)d_in[22];
  const float* Wlin = (const float*)d_in[23];
  const float* blin = (const float*)d_in[24];
  const float* Wprj = (const float*)d_in[25];
  const float* bprj = (const float*)d_in[26];
  float* out = (float*)d_out;

  const size_t SZ = (size_t)64 * 512 * 512;
  char* p = (char*)d_ws;
  unsigned short* xn  = (unsigned short*)p; p += SZ * 2;   // RevIN'd x, (B,F,L)
  unsigned short* h2  = (unsigned short*)p; p += SZ * 2;   // (B,F,L)
  unsigned short* h3  = (unsigned short*)p; p += SZ * 2;   // (B,F,L)
  unsigned short* abf = (unsigned short*)p; p += SZ * 2;   // LN out / ybuf alias
  unsigned short* q16 = (unsigned short*)p; p += SZ * 2;
  unsigned short* k16 = (unsigned short*)p; p += SZ * 2;
  unsigned short* v16 = (unsigned short*)p; p += SZ * 2;
  unsigned short* wbf = (unsigned short*)p; p += (size_t)8 * 262144 * 2;
  float* meanb = (float*)p;         p += 32768 * 4;
  float* stdb  = (float*)p;         p += 32768 * 4;
  float* ybuf  = (float*)abf;       // abf dead before feat_linear

  wconv_k<<<dim3(128, 8), 256, 0, stream>>>(tWq, tWk, tWv, tWo, fWq, fWk, fWv, fWo, wbf);
  revin_xn_k<<<8192, 256, 0, stream>>>(x, rg, rb, meanb, stdb, xn);

  // --- temporal attention block (tokens = l, dim = F) ---
  tln_k<<<dim3(16, 64), 256, 0, stream>>>(xn, n1g, n1b, abf);
  gemm_qkv3_k<<<3072, 256, 0, stream>>>(abf, wbf, tbq, tbk, tbv, q16, k16, v16);
  kv_attn_k<<<512, 256, 0, stream>>>(q16, k16, v16);
  gemm_std_k<1, 0, 1><<<1024, 256, 0, stream>>>(q16, wbf + 3 * 262144, tbo, xn, h2);

  // --- feature attention block (tokens = f, dim = L) ---
  ln_k<<<8192, 256, 0, stream>>>(h2, n2g, n2b, abf);
  gemm_qkv3_k<<<3072, 256, 0, stream>>>(abf, wbf + 4 * 262144, fbq, fbk, fbv, q16, k16, v16);
  kv_attn_k<<<512, 256, 0, stream>>>(q16, k16, v16);
  gemm_std_k<0, 0, 1><<<1024, 256, 0, stream>>>(q16, wbf + 7 * 262144, fbo, h2, h3);

  // tail
  feat_linear_k<<<512, 256, 0, stream>>>(h3, Wlin, blin, ybuf);
  final_out_k<<<64, 256, 0, stream>>>(ybuf, meanb, stdb, rg, rb, Wprj, bprj, out);
}

// Round 16
// 409.570 us; speedup vs baseline: 1.4451x; 1.4451x over previous
//
#include <hip/hip_runtime.h>
#include <hip/hip_bf16.h>
#include <cstdint>
#include <cstddef>

// LinearCrypto MI355X round 16: r15's 32KB-LDS two-pass epilogue but WITHOUT
// the VGPR cap (launch_bounds(256,4), r14-style) -> 5 blocks/CU via LDS only,
// no accumulator spills. B=64, F=512, L=512, P=96, H=8, M=32768.

#define EPS_ATTN 1e-6f
#define EPS_LN   1e-5f
#define EPS_REVIN 1e-5f

typedef __attribute__((ext_vector_type(8))) short bf16x8;
typedef __attribute__((ext_vector_type(4))) float f32x4;
typedef __attribute__((ext_vector_type(8))) unsigned short u16x8;

__device__ __forceinline__ float bf2f(unsigned short u) {
  unsigned int x = ((unsigned int)u) << 16;
  return __builtin_bit_cast(float, x);
}
__device__ __forceinline__ unsigned short f2bf(float f) {
  __hip_bfloat16 h = __float2bfloat16(f);
  return __builtin_bit_cast(unsigned short, h);
}
__device__ __forceinline__ void gload16(const void* g, void* l) {
  __builtin_amdgcn_global_load_lds(
      (const __attribute__((address_space(1))) void*)g,
      (__attribute__((address_space(3))) void*)l, 16, 0, 0);
}

// ---------- RevIN stats + normalized bf16 copy xn (B,F,L) ----------
__global__ __launch_bounds__(256) void revin_xn_k(const float* __restrict__ x,
                                                  const float* __restrict__ rg,
                                                  const float* __restrict__ rb,
                                                  float* __restrict__ meanb,
                                                  float* __restrict__ stdb,
                                                  unsigned short* __restrict__ xn) {
  int wid = threadIdx.x >> 6, lane = threadIdx.x & 63;
  int row = blockIdx.x * 4 + wid;               // b*512 + f
  const float* xr = x + (size_t)row * 512 + lane * 8;
  float4 a = *(const float4*)xr;
  float4 c = *(const float4*)(xr + 4);
  float s1 = a.x + a.y + a.z + a.w + c.x + c.y + c.z + c.w;
  float s2 = a.x * a.x + a.y * a.y + a.z * a.z + a.w * a.w +
             c.x * c.x + c.y * c.y + c.z * c.z + c.w * c.w;
#pragma unroll
  for (int off = 1; off < 64; off <<= 1) { s1 += __shfl_xor(s1, off); s2 += __shfl_xor(s2, off); }
  float m = s1 * (1.f / 512.f);
  float var = fmaxf((s2 - 512.f * m * m) * (1.f / 511.f), 0.f);
  float sd = sqrtf(var) + EPS_REVIN;
  int f = row & 511;
  float sc = rg[f] / sd;
  float of = rb[f] - m * sc;
  u16x8 o;
  o[0] = f2bf(a.x * sc + of); o[1] = f2bf(a.y * sc + of);
  o[2] = f2bf(a.z * sc + of); o[3] = f2bf(a.w * sc + of);
  o[4] = f2bf(c.x * sc + of); o[5] = f2bf(c.y * sc + of);
  o[6] = f2bf(c.z * sc + of); o[7] = f2bf(c.w * sc + of);
  *(u16x8*)(xn + (size_t)row * 512 + lane * 8) = o;
  if (lane == 0) { meanb[row] = m; stdb[row] = sd; }
}

// ---------- fused transpose + LayerNorm: xn (B,F,L) -> abf (B,L,F) LN'd ----------
__global__ __launch_bounds__(256) void tln_k(const unsigned short* __restrict__ xn,
                                             const float* __restrict__ g,
                                             const float* __restrict__ bq,
                                             unsigned short* __restrict__ o16) {
  __shared__ unsigned short Ts[32][528] __attribute__((aligned(16)));
  const int b = blockIdx.y, l0 = blockIdx.x * 32;
  const int tid = threadIdx.x;
#pragma unroll
  for (int it = 0; it < 8; ++it) {
    int idx = it * 256 + tid;
    int f = idx >> 2, lc = (idx & 3) * 8;
    u16x8 v = *(const u16x8*)(xn + ((size_t)b * 512 + f) * 512 + l0 + lc);
#pragma unroll
    for (int j = 0; j < 8; ++j) Ts[lc + j][f] = v[j];
  }
  __syncthreads();
  const int l = tid >> 3, q = tid & 7;
  float s1 = 0.f, s2 = 0.f;
#pragma unroll
  for (int i = 0; i < 8; ++i) {
    int c = (i + q) & 7;
    bf16x8 t = *(const bf16x8*)&Ts[l][q * 64 + c * 8];
#pragma unroll
    for (int j = 0; j < 8; ++j) {
      float x = bf2f((unsigned short)t[j]);
      s1 += x; s2 += x * x;
    }
  }
#pragma unroll
  for (int off = 1; off < 8; off <<= 1) { s1 += __shfl_xor(s1, off); s2 += __shfl_xor(s2, off); }
  float m = s1 * (1.f / 512.f);
  float var = fmaxf(s2 * (1.f / 512.f) - m * m, 0.f);
  float iv = 1.f / sqrtf(var + EPS_LN);
#pragma unroll
  for (int i = 0; i < 8; ++i) {
    int c = (i + q) & 7;
    int f8 = q * 64 + c * 8;
    bf16x8 t = *(const bf16x8*)&Ts[l][f8];
    float4 g0 = *(const float4*)(g + f8);
    float4 g1 = *(const float4*)(g + f8 + 4);
    float4 b0 = *(const float4*)(bq + f8);
    float4 b1 = *(const float4*)(bq + f8 + 4);
    u16x8 o;
    o[0] = f2bf((bf2f((unsigned short)t[0]) - m) * iv * g0.x + b0.x);
    o[1] = f2bf((bf2f((unsigned short)t[1]) - m) * iv * g0.y + b0.y);
    o[2] = f2bf((bf2f((unsigned short)t[2]) - m) * iv * g0.z + b0.z);
    o[3] = f2bf((bf2f((unsigned short)t[3]) - m) * iv * g0.w + b0.w);
    o[4] = f2bf((bf2f((unsigned short)t[4]) - m) * iv * g1.x + b1.x);
    o[5] = f2bf((bf2f((unsigned short)t[5]) - m) * iv * g1.y + b1.y);
    o[6] = f2bf((bf2f((unsigned short)t[6]) - m) * iv * g1.z + b1.z);
    o[7] = f2bf((bf2f((unsigned short)t[7]) - m) * iv * g1.w + b1.w);
    *(u16x8*)&Ts[l][f8] = o;
  }
  __syncthreads();
#pragma unroll
  for (int it = 0; it < 8; ++it) {
    int idx = it * 256 + tid;
    int ll = idx >> 6, f8 = (idx & 63) * 8;
    u16x8 v = *(const u16x8*)&Ts[ll][f8];
    *(u16x8*)(o16 + ((size_t)b * 512 + l0 + ll) * 512 + f8) = v;
  }
}

// ---------- fused LayerNorm bf16 -> bf16 ----------
__global__ __launch_bounds__(256) void ln_k(const unsigned short* __restrict__ in,
                                            const float* __restrict__ g,
                                            const float* __restrict__ bq,
                                            unsigned short* __restrict__ o16) {
  int row = blockIdx.x * 4 + (threadIdx.x >> 6);
  int lane = threadIdx.x & 63;
  u16x8 u = *(const u16x8*)(in + (size_t)row * 512 + lane * 8);
  float v[8];
#pragma unroll
  for (int j = 0; j < 8; ++j) v[j] = bf2f(u[j]);
  float s1 = 0.f, s2 = 0.f;
#pragma unroll
  for (int j = 0; j < 8; ++j) { s1 += v[j]; s2 += v[j] * v[j]; }
#pragma unroll
  for (int off = 1; off < 64; off <<= 1) { s1 += __shfl_xor(s1, off); s2 += __shfl_xor(s2, off); }
  float m = s1 * (1.f / 512.f);
  float var = fmaxf(s2 * (1.f / 512.f) - m * m, 0.f);
  float iv = 1.f / sqrtf(var + EPS_LN);
  float4 g0 = *(const float4*)(g + lane * 8);
  float4 g1 = *(const float4*)(g + lane * 8 + 4);
  float4 b0 = *(const float4*)(bq + lane * 8);
  float4 b1 = *(const float4*)(bq + lane * 8 + 4);
  u16x8 o;
  o[0] = f2bf((v[0] - m) * iv * g0.x + b0.x);
  o[1] = f2bf((v[1] - m) * iv * g0.y + b0.y);
  o[2] = f2bf((v[2] - m) * iv * g0.z + b0.z);
  o[3] = f2bf((v[3] - m) * iv * g0.w + b0.w);
  o[4] = f2bf((v[4] - m) * iv * g1.x + b1.x);
  o[5] = f2bf((v[5] - m) * iv * g1.y + b1.y);
  o[6] = f2bf((v[6] - m) * iv * g1.z + b1.z);
  o[7] = f2bf((v[7] - m) * iv * g1.w + b1.w);
  *(u16x8*)(o16 + (size_t)row * 512 + lane * 8) = o;
}

// ---------- convert 8 (512x512) fp32 weights -> bf16 packed ----------
__global__ __launch_bounds__(256) void wconv_k(const float* w0, const float* w1,
                                               const float* w2, const float* w3,
                                               const float* w4, const float* w5,
                                               const float* w6, const float* w7,
                                               unsigned short* __restrict__ out) {
  const float* srcs[8] = {w0, w1, w2, w3, w4, w5, w6, w7};
  const float* s = srcs[blockIdx.y];
  size_t idx = (size_t)blockIdx.x * 2048 + threadIdx.x * 8;
  float4 v0 = *(const float4*)(s + idx);
  float4 v1 = *(const float4*)(s + idx + 4);
  u16x8 o;
  o[0] = f2bf(v0.x); o[1] = f2bf(v0.y); o[2] = f2bf(v0.z); o[3] = f2bf(v0.w);
  o[4] = f2bf(v1.x); o[5] = f2bf(v1.y); o[6] = f2bf(v1.z); o[7] = f2bf(v1.w);
  *(u16x8*)(out + (size_t)blockIdx.y * 262144 + idx) = o;
}

// ---------- GEMM core (r9: single-buffer BK=64, 2 barriers/K-step) ----------
// smem layout: A tile [0,8192) shorts, B tile [8192,16384) shorts = 32768 B.
__device__ __forceinline__ void gemm_core(const unsigned short* __restrict__ A,
                                          const unsigned short* __restrict__ W,
                                          unsigned short* smem,
                                          f32x4 (&acc)[4][4],
                                          int m0, int wrow, int tid) {
  const int w = tid >> 6, lane = tid & 63;
  const int wr = w >> 1, wc = w & 1;
  const int r8 = lane >> 3, s8 = lane & 7, gslot = s8 ^ r8;
  const unsigned short* Ag = A + (size_t)(m0 + w * 32 + r8) * 512 + gslot * 8;
  const unsigned short* Wg = W + (size_t)(wrow + w * 32 + r8) * 512 + gslot * 8;
  unsigned short* Asw = smem + w * 2048;
  unsigned short* Bsw = smem + 8192 + w * 2048;
  for (int k0 = 0; k0 < 512; k0 += 64) {
#pragma unroll
    for (int c = 0; c < 4; ++c) {
      gload16(Ag + (size_t)c * 8 * 512 + k0, Asw + c * 512);
      gload16(Wg + (size_t)c * 8 * 512 + k0, Bsw + c * 512);
    }
    __syncthreads();
#pragma unroll
    for (int s = 0; s < 2; ++s) {
      bf16x8 fa[4], fb[4];
#pragma unroll
      for (int i = 0; i < 4; ++i) {
        int ra = wr * 64 + i * 16 + (lane & 15);
        int sa = (s * 4 + (lane >> 4)) ^ (ra & 7);
        fa[i] = *(const bf16x8*)&smem[ra * 64 + sa * 8];
        int rb = wc * 64 + i * 16 + (lane & 15);
        int sb = (s * 4 + (lane >> 4)) ^ (rb & 7);
        fb[i] = *(const bf16x8*)&smem[8192 + rb * 64 + sb * 8];
      }
#pragma unroll
      for (int i = 0; i < 4; ++i)
#pragma unroll
        for (int j = 0; j < 4; ++j)
          acc[i][j] = __builtin_amdgcn_mfma_f32_16x16x32_bf16(fa[i], fb[j], acc[i][j], 0, 0, 0);
    }
    __syncthreads();
  }
}

// ---------- half-tile epilogue: Cs is 64x136 (17408 B), two passes ----------
template <int TRANS, int ACT, int RES>
__device__ __forceinline__ void gemm_epilogue(f32x4 (&acc)[4][4],
                                              unsigned short* Cs,   // [64][136]
                                              const float* __restrict__ bias,
                                              const unsigned short* __restrict__ resid,
                                              unsigned short* __restrict__ out,
                                              int m0, int n0, int tid) {
  const int w = tid >> 6, lane = tid & 63;
  const int wr = w >> 1, wc = w & 1;
  const int ro = (lane >> 4) * 4, c16 = lane & 15;
  const int splitw = TRANS ? wc : wr;
  size_t rowbase; int colbase;
  if constexpr (TRANS) { rowbase = (size_t)((m0 >> 9) * 512 + n0); colbase = m0 & 511; }
  else                 { rowbase = (size_t)m0; colbase = n0; }
#pragma unroll
  for (int half = 0; half < 2; ++half) {
    __syncthreads();
    if (splitw == half) {
#pragma unroll
      for (int j = 0; j < 4; ++j) {
        int nl = wc * 64 + j * 16 + c16;
        float bi = bias[n0 + nl];
#pragma unroll
        for (int i = 0; i < 4; ++i) {
#pragma unroll
          for (int r = 0; r < 4; ++r) {
            float v = acc[i][j][r] + bi;
            if constexpr (ACT) v = (v > 0.f) ? v + 1.f : __expf(v);
            if constexpr (TRANS) Cs[(j * 16 + c16) * 136 + wr * 64 + i * 16 + ro + r] = f2bf(v);
            else                 Cs[(i * 16 + ro + r) * 136 + nl] = f2bf(v);
          }
        }
      }
    }
    __syncthreads();
#pragma unroll
    for (int c = 0; c < 4; ++c) {
      int idx = c * 256 + tid;
      int rr = idx >> 4, c8 = (idx & 15) * 8;
      u16x8 v = *(const u16x8*)&Cs[rr * 136 + c8];
      size_t gaddr = (rowbase + half * 64 + rr) * 512 + colbase + c8;
      if constexpr (RES) {
        u16x8 rv = *(const u16x8*)(resid + gaddr);
#pragma unroll
        for (int q = 0; q < 8; ++q) v[q] = f2bf(bf2f(v[q]) + bf2f(rv[q]));
      }
      *(u16x8*)(out + gaddr) = v;
    }
  }
}

// ---------- standard GEMM dispatch (Wo): 1D grid 1024, XCD-chunked, n-inner ----------
template <int TRANS, int ACT, int RES>
__global__ __launch_bounds__(256, 4) void gemm_std_k(const unsigned short* __restrict__ A,
                                                     const unsigned short* __restrict__ W,
                                                     const float* __restrict__ bias,
                                                     const unsigned short* __restrict__ resid,
                                                     unsigned short* __restrict__ out) {
  __shared__ unsigned short smem[16384] __attribute__((aligned(16)));   // 32768 B
  const int tid = threadIdx.x;
  const int bid = blockIdx.x;
  const int nb = (bid & 7) * 128 + (bid >> 3);   // bijective, 1024 % 8 == 0
  const int m0 = (nb >> 2) * 128;
  const int n0 = (nb & 3) * 128;
  f32x4 acc[4][4] = {};
  gemm_core(A, W, smem, acc, m0, n0, tid);
  gemm_epilogue<TRANS, ACT, RES>(acc, smem, bias, resid, out, m0, n0, tid);
}

// ---------- fused QKV GEMM: grid 3072, 12 n-tiles per A-panel adjacent ----------
__global__ __launch_bounds__(256, 4) void gemm_qkv3_k(const unsigned short* __restrict__ A,
                                                      const unsigned short* __restrict__ Wqkv,
                                                      const float* __restrict__ bq,
                                                      const float* __restrict__ bk,
                                                      const float* __restrict__ bv,
                                                      unsigned short* __restrict__ Q,
                                                      unsigned short* __restrict__ K,
                                                      unsigned short* __restrict__ V) {
  __shared__ unsigned short smem[16384] __attribute__((aligned(16)));   // 32768 B
  const int tid = threadIdx.x;
  const unsigned int bid = blockIdx.x;
  const unsigned int nb = (bid & 7) * 384 + (bid >> 3);  // bijective, 3072 % 8 == 0
  const int mi = nb / 12, ni = nb % 12;                  // 12 consecutive share A-panel
  const int m0 = mi * 128;
  const int mat = ni >> 2;                               // 0=Q, 1=K, 2=V
  const int n0 = (ni & 3) * 128;
  f32x4 acc[4][4] = {};
  gemm_core(A, Wqkv, smem, acc, m0, mat * 512 + n0, tid);

  const float* bias = (mat == 0) ? bq : (mat == 1) ? bk : bv;
  unsigned short* out = (mat == 0) ? Q : (mat == 1) ? K : V;
  const bool trans = (mat > 0);
  const bool act = (mat < 2);

  const int w = tid >> 6, lane = tid & 63;
  const int wr = w >> 1, wc = w & 1;
  const int ro = (lane >> 4) * 4, c16 = lane & 15;
  unsigned short* Cs = smem;
  const int splitw = trans ? wc : wr;
  size_t rowbase = trans ? (size_t)((m0 >> 9) * 512 + n0) : (size_t)m0;
  int colbase = trans ? (m0 & 511) : n0;
#pragma unroll
  for (int half = 0; half < 2; ++half) {
    __syncthreads();
    if (splitw == half) {
#pragma unroll
      for (int j = 0; j < 4; ++j) {
        int nl = wc * 64 + j * 16 + c16;
        float bi = bias[n0 + nl];
#pragma unroll
        for (int i = 0; i < 4; ++i) {
#pragma unroll
          for (int r = 0; r < 4; ++r) {
            float v = acc[i][j][r] + bi;
            if (act) v = (v > 0.f) ? v + 1.f : __expf(v);
            if (trans) Cs[(j * 16 + c16) * 136 + wr * 64 + i * 16 + ro + r] = f2bf(v);
            else       Cs[(i * 16 + ro + r) * 136 + nl] = f2bf(v);
          }
        }
      }
    }
    __syncthreads();
#pragma unroll
    for (int c = 0; c < 4; ++c) {
      int idx = c * 256 + tid;
      int rr = idx >> 4, c8 = (idx & 15) * 8;
      u16x8 v = *(const u16x8*)&Cs[rr * 136 + c8];
      *(u16x8*)(out + (rowbase + half * 64 + rr) * 512 + colbase + c8) = v;
    }
  }
}

// ---------- fused kv+attn: per (b,h): KVT+Z in LDS, then O in-place over Q ----------
__global__ __launch_bounds__(256) void kv_attn_k(unsigned short* __restrict__ Q16,
                                                 const unsigned short* __restrict__ KT,
                                                 const unsigned short* __restrict__ VT) {
  __shared__ unsigned short kvs[4096] __attribute__((aligned(16)));  // 64 e x 128B
  __shared__ float Zs[64];
  const int bh = blockIdx.x, b = bh >> 3, h = bh & 7;
  const int tid = threadIdx.x, w = tid >> 6, lane = tid & 63;
  const int r16 = lane & 15, g = lane >> 4;

  // phase 1: KVT[e][d] = sum_n VT[e][n]*KT[d][n]; Z[d] = sum_n KT[d][n]
  const unsigned short* vb = VT + ((size_t)bh * 64 + w * 16 + r16) * 512 + g * 8;
  const unsigned short* kb = KT + ((size_t)bh * 64 + r16) * 512 + g * 8;
  const short ob = (short)0x3F80;                 // bf16 1.0
  const bf16x8 onesf = {ob, ob, ob, ob, ob, ob, ob, ob};
  f32x4 acc[4] = {}, zacc[4] = {};
  for (int n0 = 0; n0 < 512; n0 += 32) {
    bf16x8 vf = *(const bf16x8*)(vb + n0);
#pragma unroll
    for (int j = 0; j < 4; ++j) {
      bf16x8 kf = *(const bf16x8*)(kb + (size_t)j * 16 * 512 + n0);
      acc[j] = __builtin_amdgcn_mfma_f32_16x16x32_bf16(vf, kf, acc[j], 0, 0, 0);
      zacc[j] = __builtin_amdgcn_mfma_f32_16x16x32_bf16(onesf, kf, zacc[j], 0, 0, 0);
    }
  }
#pragma unroll
  for (int j = 0; j < 4; ++j)
#pragma unroll
    for (int r = 0; r < 4; ++r) {
      int e = w * 16 + g * 4 + r, d = j * 16 + r16;
      int byte = e * 128 + ((((d >> 3) ^ (e & 7)) << 4)) + (d & 7) * 2;
      *(unsigned short*)((char*)kvs + byte) = f2bf(acc[j][r]);
    }
  if (w == 0 && g == 0) {
#pragma unroll
    for (int j = 0; j < 4; ++j) Zs[j * 16 + r16] = zacc[j][0];
  }
  __syncthreads();

  // phase 2: O = (Q @ KVT^T)/(Q.Z+eps); wave w owns rows w*128..+128 of batch b
#pragma unroll
  for (int i = 0; i < 8; ++i) {
    int mrow = b * 512 + w * 128 + i * 16;
    const unsigned short* qrow = Q16 + (size_t)(mrow + r16) * 512 + h * 64;
    bf16x8 q0 = *(const bf16x8*)(qrow + g * 8);
    bf16x8 q1 = *(const bf16x8*)(qrow + 32 + g * 8);
    float np = 0.f;
#pragma unroll
    for (int q = 0; q < 8; ++q) np = fmaf(bf2f((unsigned short)q0[q]), Zs[g * 8 + q], np);
#pragma unroll
    for (int q = 0; q < 8; ++q) np = fmaf(bf2f((unsigned short)q1[q]), Zs[32 + g * 8 + q], np);
    f32x4 a2[4] = {};
#pragma unroll
    for (int j = 0; j < 4; ++j) {
      int e = j * 16 + r16;
      int byte0 = e * 128, sw = (e & 7) << 4;
      bf16x8 k0 = *(const bf16x8*)((char*)kvs + ((byte0 + g * 16) ^ sw));
      bf16x8 k1 = *(const bf16x8*)((char*)kvs + ((byte0 + 64 + g * 16) ^ sw));
      a2[j] = __builtin_amdgcn_mfma_f32_16x16x32_bf16(q0, k0, a2[j], 0, 0, 0);
      a2[j] = __builtin_amdgcn_mfma_f32_16x16x32_bf16(q1, k1, a2[j], 0, 0, 0);
    }
    np += __shfl_xor(np, 16);
    np += __shfl_xor(np, 32);
    float inv = 1.f / (np + EPS_ATTN);
    float inv4[4];
#pragma unroll
    for (int r = 0; r < 4; ++r) inv4[r] = __shfl(inv, g * 4 + r);
    int orow0 = mrow + g * 4;
#pragma unroll
    for (int j = 0; j < 4; ++j)
#pragma unroll
      for (int r = 0; r < 4; ++r)
        Q16[(size_t)(orow0 + r) * 512 + h * 64 + j * 16 + r16] = f2bf(a2[j][r] * inv4[r]);
  }
}

// ---------- feat_linear via MFMA ----------
__global__ __launch_bounds__(256) void feat_linear_k(const unsigned short* __restrict__ h3,
                                                     const float* __restrict__ Wlin,
                                                     const float* __restrict__ blin,
                                                     float* __restrict__ Y) {
  __shared__ unsigned short As[64 * 64] __attribute__((aligned(16)));
  __shared__ unsigned short Bs[96 * 64] __attribute__((aligned(16)));
  const int f = blockIdx.x;
  const int tid = threadIdx.x;
  const int w = tid >> 6, lane = tid & 63;
  const int r16 = lane & 15, g = lane >> 4;
  const int r8 = lane >> 3, s8 = lane & 7, gs = s8 ^ r8;

  f32x4 acc[6] = {};
  for (int k0 = 0; k0 < 512; k0 += 64) {
#pragma unroll
    for (int c = 0; c < 2; ++c) {
      int row = w * 16 + c * 8 + r8;
      gload16(h3 + ((size_t)row * 512 + f) * 512 + k0 + gs * 8,
              As + (w * 16 + c * 8) * 64);
    }
#pragma unroll
    for (int it = 0; it < 3; ++it) {
      int idx = it * 256 + tid;
      int pp = idx >> 3, sl = idx & 7;
      const float* src = Wlin + ((size_t)f * 96 + pp) * 512 + k0 + sl * 8;
      float4 v0 = *(const float4*)src;
      float4 v1 = *(const float4*)(src + 4);
      u16x8 o;
      o[0] = f2bf(v0.x); o[1] = f2bf(v0.y); o[2] = f2bf(v0.z); o[3] = f2bf(v0.w);
      o[4] = f2bf(v1.x); o[5] = f2bf(v1.y); o[6] = f2bf(v1.z); o[7] = f2bf(v1.w);
      *(u16x8*)&Bs[pp * 64 + (sl ^ (pp & 7)) * 8] = o;
    }
    __syncthreads();
#pragma unroll
    for (int s = 0; s < 2; ++s) {
      int arow = w * 16 + r16;
      bf16x8 fa = *(const bf16x8*)&As[arow * 64 + (((s * 4 + g) ^ (arow & 7)) * 8)];
#pragma unroll
      for (int n = 0; n < 6; ++n) {
        int brow = n * 16 + r16;
        bf16x8 fb = *(const bf16x8*)&Bs[brow * 64 + (((s * 4 + g) ^ (brow & 7)) * 8)];
        acc[n] = __builtin_amdgcn_mfma_f32_16x16x32_bf16(fa, fb, acc[n], 0, 0, 0);
      }
    }
    __syncthreads();
  }
  const int b0 = w * 16 + g * 4;
#pragma unroll
  for (int n = 0; n < 6; ++n) {
    float bi = blin[f * 96 + n * 16 + r16];
#pragma unroll
    for (int r = 0; r < 4; ++r)
      Y[((size_t)(b0 + r) * 512 + f) * 96 + n * 16 + r16] = acc[n][r] + bi;
  }
}

// ---------- final: denorm + projector ----------
__global__ __launch_bounds__(256) void final_out_k(const float* __restrict__ Y,
                                                   const float* __restrict__ meanb,
                                                   const float* __restrict__ stdb,
                                                   const float* __restrict__ rg,
                                                   const float* __restrict__ rb,
                                                   const float* __restrict__ Wproj,
                                                   const float* __restrict__ bproj,
                                                   float* __restrict__ out) {
  int b = blockIdx.x;
  __shared__ float cs[512];
  __shared__ float kred[4];
  int t = threadIdx.x;
  float kpart = 0.f;
  for (int f = t; f < 512; f += 256) {
    float sd = stdb[b * 512 + f], mn = meanb[b * 512 + f];
    float g = rg[f], rbv = rb[f], wp = Wproj[f];
    float c = wp * sd / g;
    cs[f] = c;
    kpart += wp * mn - c * rbv;
  }
#pragma unroll
  for (int off = 32; off; off >>= 1) kpart += __shfl_down(kpart, off);
  int wid = t >> 6, lane = t & 63;
  if (lane == 0) kred[wid] = kpart;
  __syncthreads();
  float K = kred[0] + kred[1] + kred[2] + kred[3] + bproj[0];
  if (t < 96) {
    float acc = 0.f;
    for (int f = 0; f < 512; ++f) acc = fmaf(cs[f], Y[((size_t)b * 512 + f) * 96 + t], acc);
    out[b * 96 + t] = acc + K;
  }
}

extern "C" void kernel_launch(void* const* d_in, const int* in_sizes, int n_in,
                              void* d_out, int out_size, void* d_ws, size_t ws_size,
                              hipStream_t stream) {
  const float* x    = (const float*)d_in[0];
  const float* rg   = (const float*)d_in[1];
  const float* rb   = (const float*)d_in[2];
  const float* n1g  = (const float*)d_in[3];
  const float* n1b  = (const float*)d_in[4];
  const float* n2g  = (const float*)d_in[5];
  const float* n2b  = (const float*)d_in[6];
  const float* tWq  = (const float*)d_in[7];
  const float* tbq  = (const float*)d_in[8];
  const float* tWk  = (const float*)d_in[9];
  const float* tbk  = (const float*)d_in[10];
  const float* tWv  = (const float*)d_in[11];
  const float* tbv  = (const float*)d_in[12];
  const float* tWo  = (const float*)d_in[13];
  const float* tbo  = (const float*)d_in[14];
  const float* fWq  = (const float*)d_in[15];
  const float* fbq  = (const float*)d_in[16];
  const float* fWk  = (const float*)d_in[17];
  const float* fbk  = (const float*)d_in[18];
  const float* fWv  = (const float*)d_in[19];
  const float* fbv  = (const float*)d_in[20];
  const float* fWo  = (const float*)d_in[21];
  const float* fbo  = (const float*)d_in[22];
  const float* Wlin = (const float*)d_in[23];
  const float* blin = (const float*)d_in[24];
  const float* Wprj = (const float*)d_in[25];
  const float* bprj = (const float*)d_in[26];
  float* out = (float*)d_out;

  const size_t SZ = (size_t)64 * 512 * 512;
  char* p = (char*)d_ws;
  unsigned short* xn  = (unsigned short*)p; p += SZ * 2;   // RevIN'd x, (B,F,L)
  unsigned short* h2  = (unsigned short*)p; p += SZ * 2;   // (B,F,L)
  unsigned short* h3  = (unsigned short*)p; p += SZ * 2;   // (B,F,L)
  unsigned short* abf = (unsigned short*)p; p += SZ * 2;   // LN out / ybuf alias
  unsigned short* q16 = (unsigned short*)p; p += SZ * 2;
  unsigned short* k16 = (unsigned short*)p; p += SZ * 2;
  unsigned short* v16 = (unsigned short*)p; p += SZ * 2;
  unsigned short* wbf = (unsigned short*)p; p += (size_t)8 * 262144 * 2;
  float* meanb = (float*)p;         p += 32768 * 4;
  float* stdb  = (float*)p;         p += 32768 * 4;
  float* ybuf  = (float*)abf;       // abf dead before feat_linear

  wconv_k<<<dim3(128, 8), 256, 0, stream>>>(tWq, tWk, tWv, tWo, fWq, fWk, fWv, fWo, wbf);
  revin_xn_k<<<8192, 256, 0, stream>>>(x, rg, rb, meanb, stdb, xn);

  // --- temporal attention block (tokens = l, dim = F) ---
  tln_k<<<dim3(16, 64), 256, 0, stream>>>(xn, n1g, n1b, abf);
  gemm_qkv3_k<<<3072, 256, 0, stream>>>(abf, wbf, tbq, tbk, tbv, q16, k16, v16);
  kv_attn_k<<<512, 256, 0, stream>>>(q16, k16, v16);
  gemm_std_k<1, 0, 1><<<1024, 256, 0, stream>>>(q16, wbf + 3 * 262144, tbo, xn, h2);

  // --- feature attention block (tokens = f, dim = L) ---
  ln_k<<<8192, 256, 0, stream>>>(h2, n2g, n2b, abf);
  gemm_qkv3_k<<<3072, 256, 0, stream>>>(abf, wbf + 4 * 262144, fbq, fbk, fbv, q16, k16, v16);
  kv_attn_k<<<512, 256, 0, stream>>>(q16, k16, v16);
  gemm_std_k<0, 0, 1><<<1024, 256, 0, stream>>>(q16, wbf + 7 * 262144, fbo, h2, h3);

  // tail
  feat_linear_k<<<512, 256, 0, stream>>>(h3, Wlin, blin, ybuf);
  final_out_k<<<64, 256, 0, stream>>>(ybuf, meanb, stdb, rg, rb, Wprj, bprj, out);
}

// Round 17
// 372.763 us; speedup vs baseline: 1.5878x; 1.0987x over previous
//
#include <hip/hip_runtime.h>
#include <hip/hip_bf16.h>
#include <cstdint>
#include <cstddef>

// LinearCrypto MI355X round 17: revert to round-14 best-known state (372us).
// Plain 2-barrier 128^2 MFMA core @4 blocks/CU, fused QKV (n-inner XCD swizzle),
// fused kv+attn, MFMA feat_linear, fused norms, bf16 stream.
// B=64, F=512, L=512, P=96, H=8, hd=64, M=B*512=32768

#define EPS_ATTN 1e-6f
#define EPS_LN   1e-5f
#define EPS_REVIN 1e-5f

typedef __attribute__((ext_vector_type(8))) short bf16x8;
typedef __attribute__((ext_vector_type(4))) float f32x4;
typedef __attribute__((ext_vector_type(8))) unsigned short u16x8;

__device__ __forceinline__ float bf2f(unsigned short u) {
  unsigned int x = ((unsigned int)u) << 16;
  return __builtin_bit_cast(float, x);
}
__device__ __forceinline__ unsigned short f2bf(float f) {
  __hip_bfloat16 h = __float2bfloat16(f);
  return __builtin_bit_cast(unsigned short, h);
}
__device__ __forceinline__ void gload16(const void* g, void* l) {
  __builtin_amdgcn_global_load_lds(
      (const __attribute__((address_space(1))) void*)g,
      (__attribute__((address_space(3))) void*)l, 16, 0, 0);
}

// ---------- RevIN stats + normalized bf16 copy xn (B,F,L) ----------
__global__ __launch_bounds__(256) void revin_xn_k(const float* __restrict__ x,
                                                  const float* __restrict__ rg,
                                                  const float* __restrict__ rb,
                                                  float* __restrict__ meanb,
                                                  float* __restrict__ stdb,
                                                  unsigned short* __restrict__ xn) {
  int wid = threadIdx.x >> 6, lane = threadIdx.x & 63;
  int row = blockIdx.x * 4 + wid;               // b*512 + f
  const float* xr = x + (size_t)row * 512 + lane * 8;
  float4 a = *(const float4*)xr;
  float4 c = *(const float4*)(xr + 4);
  float s1 = a.x + a.y + a.z + a.w + c.x + c.y + c.z + c.w;
  float s2 = a.x * a.x + a.y * a.y + a.z * a.z + a.w * a.w +
             c.x * c.x + c.y * c.y + c.z * c.z + c.w * c.w;
#pragma unroll
  for (int off = 1; off < 64; off <<= 1) { s1 += __shfl_xor(s1, off); s2 += __shfl_xor(s2, off); }
  float m = s1 * (1.f / 512.f);
  float var = fmaxf((s2 - 512.f * m * m) * (1.f / 511.f), 0.f);
  float sd = sqrtf(var) + EPS_REVIN;
  int f = row & 511;
  float sc = rg[f] / sd;
  float of = rb[f] - m * sc;
  u16x8 o;
  o[0] = f2bf(a.x * sc + of); o[1] = f2bf(a.y * sc + of);
  o[2] = f2bf(a.z * sc + of); o[3] = f2bf(a.w * sc + of);
  o[4] = f2bf(c.x * sc + of); o[5] = f2bf(c.y * sc + of);
  o[6] = f2bf(c.z * sc + of); o[7] = f2bf(c.w * sc + of);
  *(u16x8*)(xn + (size_t)row * 512 + lane * 8) = o;
  if (lane == 0) { meanb[row] = m; stdb[row] = sd; }
}

// ---------- fused transpose + LayerNorm: xn (B,F,L) -> abf (B,L,F) LN'd ----------
__global__ __launch_bounds__(256) void tln_k(const unsigned short* __restrict__ xn,
                                             const float* __restrict__ g,
                                             const float* __restrict__ bq,
                                             unsigned short* __restrict__ o16) {
  __shared__ unsigned short Ts[32][528] __attribute__((aligned(16)));
  const int b = blockIdx.y, l0 = blockIdx.x * 32;
  const int tid = threadIdx.x;
#pragma unroll
  for (int it = 0; it < 8; ++it) {
    int idx = it * 256 + tid;
    int f = idx >> 2, lc = (idx & 3) * 8;
    u16x8 v = *(const u16x8*)(xn + ((size_t)b * 512 + f) * 512 + l0 + lc);
#pragma unroll
    for (int j = 0; j < 8; ++j) Ts[lc + j][f] = v[j];
  }
  __syncthreads();
  const int l = tid >> 3, q = tid & 7;
  float s1 = 0.f, s2 = 0.f;
#pragma unroll
  for (int i = 0; i < 8; ++i) {
    int c = (i + q) & 7;
    bf16x8 t = *(const bf16x8*)&Ts[l][q * 64 + c * 8];
#pragma unroll
    for (int j = 0; j < 8; ++j) {
      float x = bf2f((unsigned short)t[j]);
      s1 += x; s2 += x * x;
    }
  }
#pragma unroll
  for (int off = 1; off < 8; off <<= 1) { s1 += __shfl_xor(s1, off); s2 += __shfl_xor(s2, off); }
  float m = s1 * (1.f / 512.f);
  float var = fmaxf(s2 * (1.f / 512.f) - m * m, 0.f);
  float iv = 1.f / sqrtf(var + EPS_LN);
#pragma unroll
  for (int i = 0; i < 8; ++i) {
    int c = (i + q) & 7;
    int f8 = q * 64 + c * 8;
    bf16x8 t = *(const bf16x8*)&Ts[l][f8];
    float4 g0 = *(const float4*)(g + f8);
    float4 g1 = *(const float4*)(g + f8 + 4);
    float4 b0 = *(const float4*)(bq + f8);
    float4 b1 = *(const float4*)(bq + f8 + 4);
    u16x8 o;
    o[0] = f2bf((bf2f((unsigned short)t[0]) - m) * iv * g0.x + b0.x);
    o[1] = f2bf((bf2f((unsigned short)t[1]) - m) * iv * g0.y + b0.y);
    o[2] = f2bf((bf2f((unsigned short)t[2]) - m) * iv * g0.z + b0.z);
    o[3] = f2bf((bf2f((unsigned short)t[3]) - m) * iv * g0.w + b0.w);
    o[4] = f2bf((bf2f((unsigned short)t[4]) - m) * iv * g1.x + b1.x);
    o[5] = f2bf((bf2f((unsigned short)t[5]) - m) * iv * g1.y + b1.y);
    o[6] = f2bf((bf2f((unsigned short)t[6]) - m) * iv * g1.z + b1.z);
    o[7] = f2bf((bf2f((unsigned short)t[7]) - m) * iv * g1.w + b1.w);
    *(u16x8*)&Ts[l][f8] = o;
  }
  __syncthreads();
#pragma unroll
  for (int it = 0; it < 8; ++it) {
    int idx = it * 256 + tid;
    int ll = idx >> 6, f8 = (idx & 63) * 8;
    u16x8 v = *(const u16x8*)&Ts[ll][f8];
    *(u16x8*)(o16 + ((size_t)b * 512 + l0 + ll) * 512 + f8) = v;
  }
}

// ---------- fused LayerNorm bf16 -> bf16 ----------
__global__ __launch_bounds__(256) void ln_k(const unsigned short* __restrict__ in,
                                            const float* __restrict__ g,
                                            const float* __restrict__ bq,
                                            unsigned short* __restrict__ o16) {
  int row = blockIdx.x * 4 + (threadIdx.x >> 6);
  int lane = threadIdx.x & 63;
  u16x8 u = *(const u16x8*)(in + (size_t)row * 512 + lane * 8);
  float v[8];
#pragma unroll
  for (int j = 0; j < 8; ++j) v[j] = bf2f(u[j]);
  float s1 = 0.f, s2 = 0.f;
#pragma unroll
  for (int j = 0; j < 8; ++j) { s1 += v[j]; s2 += v[j] * v[j]; }
#pragma unroll
  for (int off = 1; off < 64; off <<= 1) { s1 += __shfl_xor(s1, off); s2 += __shfl_xor(s2, off); }
  float m = s1 * (1.f / 512.f);
  float var = fmaxf(s2 * (1.f / 512.f) - m * m, 0.f);
  float iv = 1.f / sqrtf(var + EPS_LN);
  float4 g0 = *(const float4*)(g + lane * 8);
  float4 g1 = *(const float4*)(g + lane * 8 + 4);
  float4 b0 = *(const float4*)(bq + lane * 8);
  float4 b1 = *(const float4*)(bq + lane * 8 + 4);
  u16x8 o;
  o[0] = f2bf((v[0] - m) * iv * g0.x + b0.x);
  o[1] = f2bf((v[1] - m) * iv * g0.y + b0.y);
  o[2] = f2bf((v[2] - m) * iv * g0.z + b0.z);
  o[3] = f2bf((v[3] - m) * iv * g0.w + b0.w);
  o[4] = f2bf((v[4] - m) * iv * g1.x + b1.x);
  o[5] = f2bf((v[5] - m) * iv * g1.y + b1.y);
  o[6] = f2bf((v[6] - m) * iv * g1.z + b1.z);
  o[7] = f2bf((v[7] - m) * iv * g1.w + b1.w);
  *(u16x8*)(o16 + (size_t)row * 512 + lane * 8) = o;
}

// ---------- convert 8 (512x512) fp32 weights -> bf16 packed ----------
__global__ __launch_bounds__(256) void wconv_k(const float* w0, const float* w1,
                                               const float* w2, const float* w3,
                                               const float* w4, const float* w5,
                                               const float* w6, const float* w7,
                                               unsigned short* __restrict__ out) {
  const float* srcs[8] = {w0, w1, w2, w3, w4, w5, w6, w7};
  const float* s = srcs[blockIdx.y];
  size_t idx = (size_t)blockIdx.x * 2048 + threadIdx.x * 8;
  float4 v0 = *(const float4*)(s + idx);
  float4 v1 = *(const float4*)(s + idx + 4);
  u16x8 o;
  o[0] = f2bf(v0.x); o[1] = f2bf(v0.y); o[2] = f2bf(v0.z); o[3] = f2bf(v0.w);
  o[4] = f2bf(v1.x); o[5] = f2bf(v1.y); o[6] = f2bf(v1.z); o[7] = f2bf(v1.w);
  *(u16x8*)(out + (size_t)blockIdx.y * 262144 + idx) = o;
}

// ---------- GEMM core (r9: single-buffer BK=64, 2 barriers/K-step) ----------
__device__ __forceinline__ void gemm_core(const unsigned short* __restrict__ A,
                                          const unsigned short* __restrict__ W,
                                          unsigned short* smem,
                                          f32x4 (&acc)[4][4],
                                          int m0, int wrow, int tid) {
  const int w = tid >> 6, lane = tid & 63;
  const int wr = w >> 1, wc = w & 1;
  const int r8 = lane >> 3, s8 = lane & 7, gslot = s8 ^ r8;
  const unsigned short* Ag = A + (size_t)(m0 + w * 32 + r8) * 512 + gslot * 8;
  const unsigned short* Wg = W + (size_t)(wrow + w * 32 + r8) * 512 + gslot * 8;
  unsigned short* Asw = smem + w * 2048;
  unsigned short* Bsw = smem + 8192 + w * 2048;
  for (int k0 = 0; k0 < 512; k0 += 64) {
#pragma unroll
    for (int c = 0; c < 4; ++c) {
      gload16(Ag + (size_t)c * 8 * 512 + k0, Asw + c * 512);
      gload16(Wg + (size_t)c * 8 * 512 + k0, Bsw + c * 512);
    }
    __syncthreads();
#pragma unroll
    for (int s = 0; s < 2; ++s) {
      bf16x8 fa[4], fb[4];
#pragma unroll
      for (int i = 0; i < 4; ++i) {
        int ra = wr * 64 + i * 16 + (lane & 15);
        int sa = (s * 4 + (lane >> 4)) ^ (ra & 7);
        fa[i] = *(const bf16x8*)&smem[ra * 64 + sa * 8];
        int rb = wc * 64 + i * 16 + (lane & 15);
        int sb = (s * 4 + (lane >> 4)) ^ (rb & 7);
        fb[i] = *(const bf16x8*)&smem[8192 + rb * 64 + sb * 8];
      }
#pragma unroll
      for (int i = 0; i < 4; ++i)
#pragma unroll
        for (int j = 0; j < 4; ++j)
          acc[i][j] = __builtin_amdgcn_mfma_f32_16x16x32_bf16(fa[i], fb[j], acc[i][j], 0, 0, 0);
    }
    __syncthreads();
  }
}

// ---------- templated epilogue (Wo GEMMs) ----------
template <int TRANS, int ACT, int RES>
__device__ __forceinline__ void gemm_epilogue(f32x4 (&acc)[4][4],
                                              unsigned short* Cs,   // [128][136]
                                              const float* __restrict__ bias,
                                              const unsigned short* __restrict__ resid,
                                              unsigned short* __restrict__ out,
                                              int m0, int n0, int tid) {
  const int w = tid >> 6, lane = tid & 63;
  const int wr = w >> 1, wc = w & 1;
  const int ro = (lane >> 4) * 4, c16 = lane & 15;
#pragma unroll
  for (int j = 0; j < 4; ++j) {
    int nl = wc * 64 + j * 16 + c16;
    float bi = bias[n0 + nl];
#pragma unroll
    for (int i = 0; i < 4; ++i) {
      int ml = wr * 64 + i * 16 + ro;
#pragma unroll
      for (int r = 0; r < 4; ++r) {
        float v = acc[i][j][r] + bi;
        if constexpr (ACT) v = (v > 0.f) ? v + 1.f : __expf(v);
        if constexpr (TRANS) Cs[nl * 136 + ml + r] = f2bf(v);
        else                 Cs[(ml + r) * 136 + nl] = f2bf(v);
      }
    }
  }
  __syncthreads();
  size_t rowbase; int colbase;
  if constexpr (TRANS) { rowbase = (size_t)((m0 >> 9) * 512 + n0); colbase = m0 & 511; }
  else                 { rowbase = (size_t)m0; colbase = n0; }
#pragma unroll
  for (int c = 0; c < 8; ++c) {
    int idx = c * 256 + tid;
    int rr = idx >> 4, c8 = (idx & 15) * 8;
    u16x8 v = *(const u16x8*)&Cs[rr * 136 + c8];
    size_t gaddr = (rowbase + rr) * 512 + colbase + c8;
    if constexpr (RES) {
      u16x8 rv = *(const u16x8*)(resid + gaddr);
#pragma unroll
      for (int q = 0; q < 8; ++q) v[q] = f2bf(bf2f(v[q]) + bf2f(rv[q]));
    }
    *(u16x8*)(out + gaddr) = v;
  }
}

// ---------- standard GEMM dispatch (Wo): 1D grid 1024, XCD-chunked, n-inner ----------
template <int TRANS, int ACT, int RES>
__global__ __launch_bounds__(256, 4) void gemm_std_k(const unsigned short* __restrict__ A,
                                                     const unsigned short* __restrict__ W,
                                                     const float* __restrict__ bias,
                                                     const unsigned short* __restrict__ resid,
                                                     unsigned short* __restrict__ out) {
  __shared__ unsigned short smem[17408] __attribute__((aligned(16)));
  const int tid = threadIdx.x;
  const int bid = blockIdx.x;
  const int nb = (bid & 7) * 128 + (bid >> 3);   // bijective, 1024 % 8 == 0
  const int m0 = (nb >> 2) * 128;
  const int n0 = (nb & 3) * 128;
  f32x4 acc[4][4] = {};
  gemm_core(A, W, smem, acc, m0, n0, tid);
  gemm_epilogue<TRANS, ACT, RES>(acc, smem, bias, resid, out, m0, n0, tid);
}

// ---------- fused QKV GEMM: grid 3072, 12 n-tiles per A-panel adjacent ----------
__global__ __launch_bounds__(256, 4) void gemm_qkv3_k(const unsigned short* __restrict__ A,
                                                      const unsigned short* __restrict__ Wqkv,
                                                      const float* __restrict__ bq,
                                                      const float* __restrict__ bk,
                                                      const float* __restrict__ bv,
                                                      unsigned short* __restrict__ Q,
                                                      unsigned short* __restrict__ K,
                                                      unsigned short* __restrict__ V) {
  __shared__ unsigned short smem[17408] __attribute__((aligned(16)));
  const int tid = threadIdx.x;
  const unsigned int bid = blockIdx.x;
  const unsigned int nb = (bid & 7) * 384 + (bid >> 3);  // bijective, 3072 % 8 == 0
  const int mi = nb / 12, ni = nb % 12;                  // 12 consecutive share A-panel
  const int m0 = mi * 128;
  const int mat = ni >> 2;                               // 0=Q, 1=K, 2=V
  const int n0 = (ni & 3) * 128;
  f32x4 acc[4][4] = {};
  gemm_core(A, Wqkv, smem, acc, m0, mat * 512 + n0, tid);

  const float* bias = (mat == 0) ? bq : (mat == 1) ? bk : bv;
  unsigned short* out = (mat == 0) ? Q : (mat == 1) ? K : V;
  const bool trans = (mat > 0);
  const bool act = (mat < 2);

  const int w = tid >> 6, lane = tid & 63;
  const int wr = w >> 1, wc = w & 1;
  const int ro = (lane >> 4) * 4, c16 = lane & 15;
  unsigned short* Cs = smem;
#pragma unroll
  for (int j = 0; j < 4; ++j) {
    int nl = wc * 64 + j * 16 + c16;
    float bi = bias[n0 + nl];
#pragma unroll
    for (int i = 0; i < 4; ++i) {
      int ml = wr * 64 + i * 16 + ro;
#pragma unroll
      for (int r = 0; r < 4; ++r) {
        float v = acc[i][j][r] + bi;
        if (act) v = (v > 0.f) ? v + 1.f : __expf(v);
        int row = trans ? nl : (ml + r);
        int col = trans ? (ml + r) : nl;
        Cs[row * 136 + col] = f2bf(v);
      }
    }
  }
  __syncthreads();
  size_t rowbase = trans ? (size_t)((m0 >> 9) * 512 + n0) : (size_t)m0;
  int colbase = trans ? (m0 & 511) : n0;
#pragma unroll
  for (int c = 0; c < 8; ++c) {
    int idx = c * 256 + tid;
    int rr = idx >> 4, c8 = (idx & 15) * 8;
    u16x8 v = *(const u16x8*)&Cs[rr * 136 + c8];
    *(u16x8*)(out + (rowbase + rr) * 512 + colbase + c8) = v;
  }
}

// ---------- fused kv+attn: per (b,h): KVT+Z in LDS, then O in-place over Q ----------
__global__ __launch_bounds__(256) void kv_attn_k(unsigned short* __restrict__ Q16,
                                                 const unsigned short* __restrict__ KT,
                                                 const unsigned short* __restrict__ VT) {
  __shared__ unsigned short kvs[4096] __attribute__((aligned(16)));  // 64 e x 128B
  __shared__ float Zs[64];
  const int bh = blockIdx.x, b = bh >> 3, h = bh & 7;
  const int tid = threadIdx.x, w = tid >> 6, lane = tid & 63;
  const int r16 = lane & 15, g = lane >> 4;

  // phase 1: KVT[e][d] = sum_n VT[e][n]*KT[d][n]; Z[d] = sum_n KT[d][n]
  const unsigned short* vb = VT + ((size_t)bh * 64 + w * 16 + r16) * 512 + g * 8;
  const unsigned short* kb = KT + ((size_t)bh * 64 + r16) * 512 + g * 8;
  const short ob = (short)0x3F80;                 // bf16 1.0
  const bf16x8 onesf = {ob, ob, ob, ob, ob, ob, ob, ob};
  f32x4 acc[4] = {}, zacc[4] = {};
  for (int n0 = 0; n0 < 512; n0 += 32) {
    bf16x8 vf = *(const bf16x8*)(vb + n0);
#pragma unroll
    for (int j = 0; j < 4; ++j) {
      bf16x8 kf = *(const bf16x8*)(kb + (size_t)j * 16 * 512 + n0);
      acc[j] = __builtin_amdgcn_mfma_f32_16x16x32_bf16(vf, kf, acc[j], 0, 0, 0);
      zacc[j] = __builtin_amdgcn_mfma_f32_16x16x32_bf16(onesf, kf, zacc[j], 0, 0, 0);
    }
  }
#pragma unroll
  for (int j = 0; j < 4; ++j)
#pragma unroll
    for (int r = 0; r < 4; ++r) {
      int e = w * 16 + g * 4 + r, d = j * 16 + r16;
      int byte = e * 128 + ((((d >> 3) ^ (e & 7)) << 4)) + (d & 7) * 2;
      *(unsigned short*)((char*)kvs + byte) = f2bf(acc[j][r]);
    }
  if (w == 0 && g == 0) {
#pragma unroll
    for (int j = 0; j < 4; ++j) Zs[j * 16 + r16] = zacc[j][0];
  }
  __syncthreads();

  // phase 2: O = (Q @ KVT^T)/(Q.Z+eps); wave w owns rows w*128..+128 of batch b
#pragma unroll
  for (int i = 0; i < 8; ++i) {
    int mrow = b * 512 + w * 128 + i * 16;
    const unsigned short* qrow = Q16 + (size_t)(mrow + r16) * 512 + h * 64;
    bf16x8 q0 = *(const bf16x8*)(qrow + g * 8);
    bf16x8 q1 = *(const bf16x8*)(qrow + 32 + g * 8);
    float np = 0.f;
#pragma unroll
    for (int q = 0; q < 8; ++q) np = fmaf(bf2f((unsigned short)q0[q]), Zs[g * 8 + q], np);
#pragma unroll
    for (int q = 0; q < 8; ++q) np = fmaf(bf2f((unsigned short)q1[q]), Zs[32 + g * 8 + q], np);
    f32x4 a2[4] = {};
#pragma unroll
    for (int j = 0; j < 4; ++j) {
      int e = j * 16 + r16;
      int byte0 = e * 128, sw = (e & 7) << 4;
      bf16x8 k0 = *(const bf16x8*)((char*)kvs + ((byte0 + g * 16) ^ sw));
      bf16x8 k1 = *(const bf16x8*)((char*)kvs + ((byte0 + 64 + g * 16) ^ sw));
      a2[j] = __builtin_amdgcn_mfma_f32_16x16x32_bf16(q0, k0, a2[j], 0, 0, 0);
      a2[j] = __builtin_amdgcn_mfma_f32_16x16x32_bf16(q1, k1, a2[j], 0, 0, 0);
    }
    np += __shfl_xor(np, 16);
    np += __shfl_xor(np, 32);
    float inv = 1.f / (np + EPS_ATTN);
    float inv4[4];
#pragma unroll
    for (int r = 0; r < 4; ++r) inv4[r] = __shfl(inv, g * 4 + r);
    int orow0 = mrow + g * 4;
#pragma unroll
    for (int j = 0; j < 4; ++j)
#pragma unroll
      for (int r = 0; r < 4; ++r)
        Q16[(size_t)(orow0 + r) * 512 + h * 64 + j * 16 + r16] = f2bf(a2[j][r] * inv4[r]);
  }
}

// ---------- feat_linear via MFMA ----------
__global__ __launch_bounds__(256) void feat_linear_k(const unsigned short* __restrict__ h3,
                                                     const float* __restrict__ Wlin,
                                                     const float* __restrict__ blin,
                                                     float* __restrict__ Y) {
  __shared__ unsigned short As[64 * 64] __attribute__((aligned(16)));
  __shared__ unsigned short Bs[96 * 64] __attribute__((aligned(16)));
  const int f = blockIdx.x;
  const int tid = threadIdx.x;
  const int w = tid >> 6, lane = tid & 63;
  const int r16 = lane & 15, g = lane >> 4;
  const int r8 = lane >> 3, s8 = lane & 7, gs = s8 ^ r8;

  f32x4 acc[6] = {};
  for (int k0 = 0; k0 < 512; k0 += 64) {
#pragma unroll
    for (int c = 0; c < 2; ++c) {
      int row = w * 16 + c * 8 + r8;
      gload16(h3 + ((size_t)row * 512 + f) * 512 + k0 + gs * 8,
              As + (w * 16 + c * 8) * 64);
    }
#pragma unroll
    for (int it = 0; it < 3; ++it) {
      int idx = it * 256 + tid;
      int pp = idx >> 3, sl = idx & 7;
      const float* src = Wlin + ((size_t)f * 96 + pp) * 512 + k0 + sl * 8;
      float4 v0 = *(const float4*)src;
      float4 v1 = *(const float4*)(src + 4);
      u16x8 o;
      o[0] = f2bf(v0.x); o[1] = f2bf(v0.y); o[2] = f2bf(v0.z); o[3] = f2bf(v0.w);
      o[4] = f2bf(v1.x); o[5] = f2bf(v1.y); o[6] = f2bf(v1.z); o[7] = f2bf(v1.w);
      *(u16x8*)&Bs[pp * 64 + (sl ^ (pp & 7)) * 8] = o;
    }
    __syncthreads();
#pragma unroll
    for (int s = 0; s < 2; ++s) {
      int arow = w * 16 + r16;
      bf16x8 fa = *(const bf16x8*)&As[arow * 64 + (((s * 4 + g) ^ (arow & 7)) * 8)];
#pragma unroll
      for (int n = 0; n < 6; ++n) {
        int brow = n * 16 + r16;
        bf16x8 fb = *(const bf16x8*)&Bs[brow * 64 + (((s * 4 + g) ^ (brow & 7)) * 8)];
        acc[n] = __builtin_amdgcn_mfma_f32_16x16x32_bf16(fa, fb, acc[n], 0, 0, 0);
      }
    }
    __syncthreads();
  }
  const int b0 = w * 16 + g * 4;
#pragma unroll
  for (int n = 0; n < 6; ++n) {
    float bi = blin[f * 96 + n * 16 + r16];
#pragma unroll
    for (int r = 0; r < 4; ++r)
      Y[((size_t)(b0 + r) * 512 + f) * 96 + n * 16 + r16] = acc[n][r] + bi;
  }
}

// ---------- final: denorm + projector ----------
__global__ __launch_bounds__(256) void final_out_k(const float* __restrict__ Y,
                                                   const float* __restrict__ meanb,
                                                   const float* __restrict__ stdb,
                                                   const float* __restrict__ rg,
                                                   const float* __restrict__ rb,
                                                   const float* __restrict__ Wproj,
                                                   const float* __restrict__ bproj,
                                                   float* __restrict__ out) {
  int b = blockIdx.x;
  __shared__ float cs[512];
  __shared__ float kred[4];
  int t = threadIdx.x;
  float kpart = 0.f;
  for (int f = t; f < 512; f += 256) {
    float sd = stdb[b * 512 + f], mn = meanb[b * 512 + f];
    float g = rg[f], rbv = rb[f], wp = Wproj[f];
    float c = wp * sd / g;
    cs[f] = c;
    kpart += wp * mn - c * rbv;
  }
#pragma unroll
  for (int off = 32; off; off >>= 1) kpart += __shfl_down(kpart, off);
  int wid = t >> 6, lane = t & 63;
  if (lane == 0) kred[wid] = kpart;
  __syncthreads();
  float K = kred[0] + kred[1] + kred[2] + kred[3] + bproj[0];
  if (t < 96) {
    float acc = 0.f;
    for (int f = 0; f < 512; ++f) acc = fmaf(cs[f], Y[((size_t)b * 512 + f) * 96 + t], acc);
    out[b * 96 + t] = acc + K;
  }
}

extern "C" void kernel_launch(void* const* d_in, const int* in_sizes, int n_in,
                              void* d_out, int out_size, void* d_ws, size_t ws_size,
                              hipStream_t stream) {
  const float* x    = (const float*)d_in[0];
  const float* rg   = (const float*)d_in[1];
  const float* rb   = (const float*)d_in[2];
  const float* n1g  = (const float*)d_in[3];
  const float* n1b  = (const float*)d_in[4];
  const float* n2g  = (const float*)d_in[5];
  const float* n2b  = (const float*)d_in[6];
  const float* tWq  = (const float*)d_in[7];
  const float* tbq  = (const float*)d_in[8];
  const float* tWk  = (const float*)d_in[9];
  const float* tbk  = (const float*)d_in[10];
  const float* tWv  = (const float*)d_in[11];
  const float* tbv  = (const float*)d_in[12];
  const float* tWo  = (const float*)d_in[13];
  const float* tbo  = (const float*)d_in[14];
  const float* fWq  = (const float*)d_in[15];
  const float* fbq  = (const float*)d_in[16];
  const float* fWk  = (const float*)d_in[17];
  const float* fbk  = (const float*)d_in[18];
  const float* fWv  = (const float*)d_in[19];
  const float* fbv  = (const float*)d_in[20];
  const float* fWo  = (const float*)d_in[21];
  const float* fbo  = (const float*)d_in[22];
  const float* Wlin = (const float*)d_in[23];
  const float* blin = (const float*)d_in[24];
  const float* Wprj = (const float*)d_in[25];
  const float* bprj = (const float*)d_in[26];
  float* out = (float*)d_out;

  const size_t SZ = (size_t)64 * 512 * 512;
  char* p = (char*)d_ws;
  unsigned short* xn  = (unsigned short*)p; p += SZ * 2;   // RevIN'd x, (B,F,L)
  unsigned short* h2  = (unsigned short*)p; p += SZ * 2;   // (B,F,L)
  unsigned short* h3  = (unsigned short*)p; p += SZ * 2;   // (B,F,L)
  unsigned short* abf = (unsigned short*)p; p += SZ * 2;   // LN out / ybuf alias
  unsigned short* q16 = (unsigned short*)p; p += SZ * 2;
  unsigned short* k16 = (unsigned short*)p; p += SZ * 2;
  unsigned short* v16 = (unsigned short*)p; p += SZ * 2;
  unsigned short* wbf = (unsigned short*)p; p += (size_t)8 * 262144 * 2;
  float* meanb = (float*)p;         p += 32768 * 4;
  float* stdb  = (float*)p;         p += 32768 * 4;
  float* ybuf  = (float*)abf;       // abf dead before feat_linear

  wconv_k<<<dim3(128, 8), 256, 0, stream>>>(tWq, tWk, tWv, tWo, fWq, fWk, fWv, fWo, wbf);
  revin_xn_k<<<8192, 256, 0, stream>>>(x, rg, rb, meanb, stdb, xn);

  // --- temporal attention block (tokens = l, dim = F) ---
  tln_k<<<dim3(16, 64), 256, 0, stream>>>(xn, n1g, n1b, abf);
  gemm_qkv3_k<<<3072, 256, 0, stream>>>(abf, wbf, tbq, tbk, tbv, q16, k16, v16);
  kv_attn_k<<<512, 256, 0, stream>>>(q16, k16, v16);
  gemm_std_k<1, 0, 1><<<1024, 256, 0, stream>>>(q16, wbf + 3 * 262144, tbo, xn, h2);

  // --- feature attention block (tokens = f, dim = L) ---
  ln_k<<<8192, 256, 0, stream>>>(h2, n2g, n2b, abf);
  gemm_qkv3_k<<<3072, 256, 0, stream>>>(abf, wbf + 4 * 262144, fbq, fbk, fbv, q16, k16, v16);
  kv_attn_k<<<512, 256, 0, stream>>>(q16, k16, v16);
  gemm_std_k<0, 0, 1><<<1024, 256, 0, stream>>>(q16, wbf + 7 * 262144, fbo, h2, h3);

  // tail
  feat_linear_k<<<512, 256, 0, stream>>>(h3, Wlin, blin, ybuf);
  final_out_k<<<64, 256, 0, stream>>>(ybuf, meanb, stdb, rg, rb, Wprj, bprj, out);
}